// Round 2
// baseline (404.545 us; speedup 1.0000x reference)
//
#include <hip/hip_runtime.h>

// Dims
#define WD 128   // W_STEPS
#define ED 16    // E
#define ND 512   // B*I
#define FD 64    // F
#define PD 72    // P = 8 + F

// ---------------------------------------------------------------------------
// Prep: collapse w_ih @ weight_linear -> Wc[E][3][FD], and
//       w_ih @ bias_linear + b_ih    -> bc[E][3]        (into d_ws)
// gx[w,e,n,g] = sum_f Wc[e,g,f]*x[w,e,n,f] + bc[e,g]
// ---------------------------------------------------------------------------
__global__ __launch_bounds__(256) void gru_prep(
    const float* __restrict__ wl,   // (E,P,F)
    const float* __restrict__ bl,   // (E,P)
    const float* __restrict__ wih,  // (E,3,P)
    const float* __restrict__ bih,  // (E,3)
    float* __restrict__ ws)
{
    const int t = threadIdx.x;
    float* Wc = ws;                 // ED*3*FD = 3072 floats
    float* bc = ws + ED * 3 * FD;   // 48 floats

    #pragma unroll
    for (int k = 0; k < 12; ++k) {
        const int idx = t + 256 * k;       // 0..3071 -> (e*3+g)*64 + f
        const int f  = idx & 63;
        const int eg = idx >> 6;           // e*3+g
        const int e  = idx / 192;
        const float* a = wih + eg * PD;
        const float* w = wl + (size_t)e * PD * FD + f;
        float s = 0.0f;
        for (int p = 0; p < PD; ++p) s = fmaf(a[p], w[p * FD], s);
        Wc[idx] = s;
    }
    if (t < ED * 3) {
        const int e = t / 3;
        const float* a = wih + t * PD;
        const float* b = bl + (size_t)e * PD;
        float s = bih[t];
        for (int p = 0; p < PD; ++p) s = fmaf(a[p], b[p], s);
        bc[t] = s;
    }
}

// ---------------------------------------------------------------------------
// Main: wave-autonomous fused projection + GRU scan.
// Each wave owns 8 chains (rows). lane = r*8 + c : row r in [0,8), f-chunk c
// in [0,8) covering f = c*8..c*8+7 (two float4 per w).
// Butterfly shfl_xor (1,2,4) leaves the full 64-dot sum in every lane of each
// 8-lane group; all lanes redundantly run the scalar GRU step; lane c==0
// stores h.  Register prefetch queue depth 4, fully unrolled (static slots).
// ---------------------------------------------------------------------------
__global__ __launch_bounds__(256) void gru_main(
    const float* __restrict__ x,    // (W,E,N,F)
    const float* __restrict__ st,   // (E,N)
    const float* __restrict__ whh,  // (E,3)
    const float* __restrict__ bhh,  // (E,3)
    const float* __restrict__ ws,   // Wc + bc
    float* __restrict__ out)        // (W,E,N)
{
    const int lane = threadIdx.x & 63;
    const int gw   = (blockIdx.x << 2) + (threadIdx.x >> 6);  // 0..1023
    const int e    = gw >> 6;                                 // 0..15
    const int n    = ((gw & 63) << 3) + (lane >> 3);          // chain index
    const int c    = lane & 7;                                // f-chunk

    const float* Wc = ws;
    const float* bc = ws + ED * 3 * FD;

    const float4 wA0 = *(const float4*)(Wc + (e * 3 + 0) * FD + c * 8);
    const float4 wB0 = *(const float4*)(Wc + (e * 3 + 0) * FD + c * 8 + 4);
    const float4 wA1 = *(const float4*)(Wc + (e * 3 + 1) * FD + c * 8);
    const float4 wB1 = *(const float4*)(Wc + (e * 3 + 1) * FD + c * 8 + 4);
    const float4 wA2 = *(const float4*)(Wc + (e * 3 + 2) * FD + c * 8);
    const float4 wB2 = *(const float4*)(Wc + (e * 3 + 2) * FD + c * 8 + 4);
    const float bc0 = bc[e * 3 + 0], bc1 = bc[e * 3 + 1], bc2 = bc[e * 3 + 2];
    const float wh0 = whh[e * 3 + 0], wh1 = whh[e * 3 + 1], wh2 = whh[e * 3 + 2];
    const float bh0 = bhh[e * 3 + 0], bh1 = bhh[e * 3 + 1], bh2 = bhh[e * 3 + 2];

    float h = st[e * ND + n];

    const float* px = x + ((size_t)e * ND + n) * FD + c * 8;
    const size_t xstr = (size_t)ED * ND * FD;   // per-w stride in floats
    float* po = out + (size_t)e * ND + n;
    const size_t ostr = (size_t)ED * ND;

    // prefetch queue: w = 0..3
    float4 a0, b0, a1, b1, a2, b2, a3, b3;
    a0 = *(const float4*)px; b0 = *(const float4*)(px + 4); px += xstr;
    a1 = *(const float4*)px; b1 = *(const float4*)(px + 4); px += xstr;
    a2 = *(const float4*)px; b2 = *(const float4*)(px + 4); px += xstr;
    a3 = *(const float4*)px; b3 = *(const float4*)(px + 4); px += xstr;

#define GRU_STEP(AA, BB)                                                        \
    {                                                                           \
        float s0, s1, s2;                                                       \
        s0 = AA.x * wA0.x;            s1 = AA.x * wA1.x;            s2 = AA.x * wA2.x; \
        s0 = fmaf(AA.y, wA0.y, s0);   s1 = fmaf(AA.y, wA1.y, s1);   s2 = fmaf(AA.y, wA2.y, s2); \
        s0 = fmaf(AA.z, wA0.z, s0);   s1 = fmaf(AA.z, wA1.z, s1);   s2 = fmaf(AA.z, wA2.z, s2); \
        s0 = fmaf(AA.w, wA0.w, s0);   s1 = fmaf(AA.w, wA1.w, s1);   s2 = fmaf(AA.w, wA2.w, s2); \
        s0 = fmaf(BB.x, wB0.x, s0);   s1 = fmaf(BB.x, wB1.x, s1);   s2 = fmaf(BB.x, wB2.x, s2); \
        s0 = fmaf(BB.y, wB0.y, s0);   s1 = fmaf(BB.y, wB1.y, s1);   s2 = fmaf(BB.y, wB2.y, s2); \
        s0 = fmaf(BB.z, wB0.z, s0);   s1 = fmaf(BB.z, wB1.z, s1);   s2 = fmaf(BB.z, wB2.z, s2); \
        s0 = fmaf(BB.w, wB0.w, s0);   s1 = fmaf(BB.w, wB1.w, s1);   s2 = fmaf(BB.w, wB2.w, s2); \
        s0 += __shfl_xor(s0, 1, 64);  s1 += __shfl_xor(s1, 1, 64);  s2 += __shfl_xor(s2, 1, 64); \
        s0 += __shfl_xor(s0, 2, 64);  s1 += __shfl_xor(s1, 2, 64);  s2 += __shfl_xor(s2, 2, 64); \
        s0 += __shfl_xor(s0, 4, 64);  s1 += __shfl_xor(s1, 4, 64);  s2 += __shfl_xor(s2, 4, 64); \
        const float gh0 = fmaf(h, wh0, bh0);                                    \
        const float gh1 = fmaf(h, wh1, bh1);                                    \
        const float gh2 = fmaf(h, wh2, bh2);                                    \
        const float rr = 1.0f / (1.0f + expf(-(s0 + bc0 + gh0)));               \
        const float zz = 1.0f / (1.0f + expf(-(s1 + bc1 + gh1)));               \
        const float nn = tanhf(fmaf(rr, gh2, s2 + bc2));                        \
        h = fmaf(zz, h - nn, nn);                                               \
        if (c == 0) *po = h;                                                    \
        po += ostr;                                                             \
    }

    for (int w4 = 0; w4 < WD; w4 += 4) {
        const bool pf = (w4 + 4) < WD;
        {
            const float4 A = a0, B = b0;
            if (pf) { a0 = *(const float4*)px; b0 = *(const float4*)(px + 4); px += xstr; }
            GRU_STEP(A, B);
        }
        {
            const float4 A = a1, B = b1;
            if (pf) { a1 = *(const float4*)px; b1 = *(const float4*)(px + 4); px += xstr; }
            GRU_STEP(A, B);
        }
        {
            const float4 A = a2, B = b2;
            if (pf) { a2 = *(const float4*)px; b2 = *(const float4*)(px + 4); px += xstr; }
            GRU_STEP(A, B);
        }
        {
            const float4 A = a3, B = b3;
            if (pf) { a3 = *(const float4*)px; b3 = *(const float4*)(px + 4); px += xstr; }
            GRU_STEP(A, B);
        }
    }
#undef GRU_STEP
}

// ---------------------------------------------------------------------------
extern "C" void kernel_launch(void* const* d_in, const int* in_sizes, int n_in,
                              void* d_out, int out_size, void* d_ws, size_t ws_size,
                              hipStream_t stream)
{
    const float* x    = (const float*)d_in[0];  // inputs (W,E,B,I,F)
    const float* st   = (const float*)d_in[1];  // state  (1,E,N,1)
    const float* wl   = (const float*)d_in[2];  // weight_linear (E,P,F)
    const float* bl   = (const float*)d_in[3];  // bias_linear   (E,P)
    const float* wih  = (const float*)d_in[4];  // w_ih (E,3,P)
    const float* whh  = (const float*)d_in[5];  // w_hh (E,3)
    const float* bih  = (const float*)d_in[6];  // b_ih (E,3)
    const float* bhh  = (const float*)d_in[7];  // b_hh (E,3)
    float* out = (float*)d_out;
    float* ws  = (float*)d_ws;                  // needs 3120 floats

    hipLaunchKernelGGL(gru_prep, dim3(1), dim3(256), 0, stream,
                       wl, bl, wih, bih, ws);
    hipLaunchKernelGGL(gru_main, dim3(256), dim3(256), 0, stream,
                       x, st, whh, bhh, ws, out);
}

// Round 4
// 374.836 us; speedup vs baseline: 1.0793x; 1.0793x over previous
//
#include <hip/hip_runtime.h>

// Dims
#define WD 128   // W_STEPS
#define ED 16    // E
#define ND 512   // B*I
#define FD 64    // F
#define PD 72    // P = 8 + F

// Fast math: v_exp_f32 (exp2) + v_rcp_f32. ~1 ulp each.
#define LOG2E  1.44269504088896340736f
#define LOG2E2 2.88539008177792681472f
__device__ __forceinline__ float fast_sig(float x) {
    return __builtin_amdgcn_rcpf(1.0f + __builtin_amdgcn_exp2f(-LOG2E * x));
}
__device__ __forceinline__ float fast_tanh(float x) {
    // tanh = 1 - 2/(e^{2x}+1); exp2(+inf)->inf -> rcp->0 -> 1; exp2(-inf)->0 -> -1
    return 1.0f - 2.0f * __builtin_amdgcn_rcpf(1.0f + __builtin_amdgcn_exp2f(LOG2E2 * x));
}

// ---------------------------------------------------------------------------
// Prep: 48 blocks (one per (e,g) row), 64 threads (one per f).
//   Wc[eg][f] = sum_p wih[eg][p] * wl[e][p][f]          -> ws[0..3071]
//   bc[eg]    = sum_p wih[eg][p] * bl[e][p] + bih[eg]   -> ws[3072..3119]
// ---------------------------------------------------------------------------
__global__ __launch_bounds__(64) void gru_prep(
    const float* __restrict__ wl,   // (E,P,F)
    const float* __restrict__ bl,   // (E,P)
    const float* __restrict__ wih,  // (E,3,P)
    const float* __restrict__ bih,  // (E,3)
    float* __restrict__ ws)
{
    const int eg = blockIdx.x;          // 0..47
    const int e  = eg / 3;
    const int f  = threadIdx.x;         // 0..63

    const float* a = wih + eg * PD;
    const float* w = wl + (size_t)e * PD * FD + f;
    float s = 0.0f;
    #pragma unroll 8
    for (int p = 0; p < PD; ++p) s = fmaf(a[p], w[p * FD], s);
    ws[eg * FD + f] = s;

    // bc[eg]: 72-long dot via wave butterfly
    const float* b = bl + (size_t)e * PD;
    float pv = a[f] * b[f];
    if (f < 8) pv = fmaf(a[64 + f], b[64 + f], pv);
    pv += __shfl_xor(pv, 1, 64);
    pv += __shfl_xor(pv, 2, 64);
    pv += __shfl_xor(pv, 4, 64);
    pv += __shfl_xor(pv, 8, 64);
    pv += __shfl_xor(pv, 16, 64);
    pv += __shfl_xor(pv, 32, 64);
    if (f == 0) ws[ED * 3 * FD + eg] = pv + bih[eg];
}

// ---------------------------------------------------------------------------
// Main: 512 blocks x 256 threads = 2048 waves (2 waves/SIMD).
// Each wave owns 4 chains: lane = r*16 + c, r = chain-in-wave (0..3),
// c = f-chunk (0..15), one float4 (f = c*4..c*4+3) per lane per step.
// Butterfly xor{1,2,4,8} reduces the 64-dot within each 16-lane group;
// all lanes redundantly run the scalar GRU; lane c==0 stores h.
// Register prefetch queue depth 8, static slots (fully unrolled).
// ---------------------------------------------------------------------------
__global__ __launch_bounds__(256) void gru_main(
    const float* __restrict__ x,    // (W,E,N,F)
    const float* __restrict__ st,   // (E,N)
    const float* __restrict__ whh,  // (E,3)
    const float* __restrict__ bhh,  // (E,3)
    const float* __restrict__ ws,   // Wc[48][64] + bc[48]
    float* __restrict__ out)        // (W,E,N)
{
    const int lane = threadIdx.x & 63;
    const int gw   = (blockIdx.x << 2) + (threadIdx.x >> 6);  // 0..2047
    const int e    = gw >> 7;                                 // 0..15
    const int r    = lane >> 4;                               // 0..3
    const int n    = ((gw & 127) << 2) + r;                   // chain 0..511
    const int c    = lane & 15;                               // f-chunk

    const float* Wc = ws;
    const float* bc = ws + ED * 3 * FD;

    const float4 w0 = *(const float4*)(Wc + (e * 3 + 0) * FD + c * 4);
    const float4 w1 = *(const float4*)(Wc + (e * 3 + 1) * FD + c * 4);
    const float4 w2 = *(const float4*)(Wc + (e * 3 + 2) * FD + c * 4);
    const float wh0 = whh[e * 3 + 0], wh1 = whh[e * 3 + 1], wh2 = whh[e * 3 + 2];
    // fold bc into the hidden-side bias where legal (r,z gates); n-gate keeps
    // bc2 separate because bh2 is multiplied by r.
    const float B0 = bc[e * 3 + 0] + bhh[e * 3 + 0];
    const float B1 = bc[e * 3 + 1] + bhh[e * 3 + 1];
    const float bc2 = bc[e * 3 + 2];
    const float bh2 = bhh[e * 3 + 2];

    float h = st[e * ND + n];

    const float* px = x + ((size_t)e * ND + n) * FD + c * 4;
    const size_t xstr = (size_t)ED * ND * FD;   // per-w stride in floats
    float* po = out + (size_t)e * ND + n;
    const size_t ostr = (size_t)ED * ND;

    // prefetch queue: w = 0..7
    float4 q0, q1, q2, q3, q4, q5, q6, q7;
    q0 = *(const float4*)px; px += xstr;
    q1 = *(const float4*)px; px += xstr;
    q2 = *(const float4*)px; px += xstr;
    q3 = *(const float4*)px; px += xstr;
    q4 = *(const float4*)px; px += xstr;
    q5 = *(const float4*)px; px += xstr;
    q6 = *(const float4*)px; px += xstr;
    q7 = *(const float4*)px; px += xstr;

#define GRU_STEP(XV)                                                            \
    {                                                                           \
        float s0 = XV.x * w0.x, s1 = XV.x * w1.x, s2 = XV.x * w2.x;             \
        s0 = fmaf(XV.y, w0.y, s0); s1 = fmaf(XV.y, w1.y, s1); s2 = fmaf(XV.y, w2.y, s2); \
        s0 = fmaf(XV.z, w0.z, s0); s1 = fmaf(XV.z, w1.z, s1); s2 = fmaf(XV.z, w2.z, s2); \
        s0 = fmaf(XV.w, w0.w, s0); s1 = fmaf(XV.w, w1.w, s1); s2 = fmaf(XV.w, w2.w, s2); \
        s0 += __shfl_xor(s0, 1, 64); s1 += __shfl_xor(s1, 1, 64); s2 += __shfl_xor(s2, 1, 64); \
        s0 += __shfl_xor(s0, 2, 64); s1 += __shfl_xor(s1, 2, 64); s2 += __shfl_xor(s2, 2, 64); \
        s0 += __shfl_xor(s0, 4, 64); s1 += __shfl_xor(s1, 4, 64); s2 += __shfl_xor(s2, 4, 64); \
        s0 += __shfl_xor(s0, 8, 64); s1 += __shfl_xor(s1, 8, 64); s2 += __shfl_xor(s2, 8, 64); \
        const float rr = fast_sig(s0 + fmaf(h, wh0, B0));                       \
        const float zz = fast_sig(s1 + fmaf(h, wh1, B1));                       \
        const float nn = fast_tanh(fmaf(rr, fmaf(h, wh2, bh2), s2 + bc2));      \
        h = fmaf(zz, h - nn, nn);                                               \
        if (c == 0) *po = h;                                                    \
        po += ostr;                                                             \
    }

    for (int it = 0; it < WD / 8; ++it) {
        const bool pf = it < (WD / 8 - 1);
        { const float4 X = q0; if (pf) { q0 = *(const float4*)px; px += xstr; } GRU_STEP(X); }
        { const float4 X = q1; if (pf) { q1 = *(const float4*)px; px += xstr; } GRU_STEP(X); }
        { const float4 X = q2; if (pf) { q2 = *(const float4*)px; px += xstr; } GRU_STEP(X); }
        { const float4 X = q3; if (pf) { q3 = *(const float4*)px; px += xstr; } GRU_STEP(X); }
        { const float4 X = q4; if (pf) { q4 = *(const float4*)px; px += xstr; } GRU_STEP(X); }
        { const float4 X = q5; if (pf) { q5 = *(const float4*)px; px += xstr; } GRU_STEP(X); }
        { const float4 X = q6; if (pf) { q6 = *(const float4*)px; px += xstr; } GRU_STEP(X); }
        { const float4 X = q7; if (pf) { q7 = *(const float4*)px; px += xstr; } GRU_STEP(X); }
    }
#undef GRU_STEP
}

// ---------------------------------------------------------------------------
extern "C" void kernel_launch(void* const* d_in, const int* in_sizes, int n_in,
                              void* d_out, int out_size, void* d_ws, size_t ws_size,
                              hipStream_t stream)
{
    const float* x    = (const float*)d_in[0];  // inputs (W,E,B,I,F)
    const float* st   = (const float*)d_in[1];  // state  (1,E,N,1)
    const float* wl   = (const float*)d_in[2];  // weight_linear (E,P,F)
    const float* bl   = (const float*)d_in[3];  // bias_linear   (E,P)
    const float* wih  = (const float*)d_in[4];  // w_ih (E,3,P)
    const float* whh  = (const float*)d_in[5];  // w_hh (E,3)
    const float* bih  = (const float*)d_in[6];  // b_ih (E,3)
    const float* bhh  = (const float*)d_in[7];  // b_hh (E,3)
    float* out = (float*)d_out;
    float* ws  = (float*)d_ws;                  // needs 3120 floats

    hipLaunchKernelGGL(gru_prep, dim3(48), dim3(64), 0, stream,
                       wl, bl, wih, bih, ws);
    hipLaunchKernelGGL(gru_main, dim3(512), dim3(256), 0, stream,
                       x, st, whh, bhh, ws, out);
}